// Round 13
// baseline (384.797 us; speedup 1.0000x reference)
//
#include <hip/hip_runtime.h>

typedef unsigned short u16;
typedef __attribute__((ext_vector_type(8))) __bf16 bf16x8;
typedef __attribute__((ext_vector_type(8))) unsigned short u16x8;
typedef __attribute__((ext_vector_type(4))) float f32x4;
typedef __attribute__((ext_vector_type(16))) float f32x16;

#define BK 32
#define TILE_ELEMS (128 * BK)
// softmax scale folded into q-projection: 1/sqrt(128) * log2(e)
#define QSCALE 0.12753706518066536f

#if __has_builtin(__builtin_amdgcn_exp2f)
#define EXP2(x) __builtin_amdgcn_exp2f(x)
#else
#define EXP2(x) exp2f(x)
#endif

// Native HW convert: compiler fuses adjacent casts into v_cvt_pk_bf16_f32.
__device__ __forceinline__ u16 f32_to_bf16(float f) {
  __bf16 h = (__bf16)f;
  return __builtin_bit_cast(u16, h);
}

// async global->LDS, 16B per lane. LDS dest must be wave-uniform base;
// HW stores lane i at base + i*16.
__device__ __forceinline__ void gll16(const u16* g, u16* l) {
  __builtin_amdgcn_global_load_lds(
      (const __attribute__((address_space(1))) void*)g,
      (__attribute__((address_space(3))) void*)l, 16, 0, 0);
}

// T1 XCD-aware swizzle (m157/m192): give each XCD a contiguous wgid chunk so
// neighboring tiles (sharing A-panels / B-panels) hit the same per-XCD L2.
// Requires nwg % 8 == 0 (true for all three GEMM grids: 640 / 1024 / 512).
__device__ __forceinline__ void xcd_swz(int& bn, int& bm) {
  const int nx = gridDim.x;
  const int nwg = nx * gridDim.y;
  const int wg = blockIdx.y * nx + blockIdx.x;
  const int cpx = nwg >> 3;
  const int swz = (wg & 7) * cpx + (wg >> 3);
  bn = swz % nx;
  bm = swz / nx;
}

// ---------------- fused fp32 -> bf16 conversion (all 5 tensors) -------------
__global__ __launch_bounds__(256) void cvt_all(
    const float* __restrict__ x, const float* __restrict__ qw,
    const float* __restrict__ kvdw, const float* __restrict__ kvuw,
    const float* __restrict__ outw, u16* __restrict__ X, u16* __restrict__ W1,
    u16* __restrict__ W2, u16* __restrict__ W3, u16* __restrict__ W4) {
  int blk = blockIdx.x;
  const float* src;
  u16* dst;
  int base;
  if (blk < 8192)       { src = x;    dst = X;  base = blk; }
  else if (blk < 12288) { src = qw;   dst = W1; base = blk - 8192; }
  else if (blk < 13312) { src = kvdw; dst = W2; base = blk - 12288; }
  else if (blk < 15360) { src = kvuw; dst = W3; base = blk - 13312; }
  else                  { src = outw; dst = W4; base = blk - 15360; }
  int i = base * 1024 + threadIdx.x * 4;
  float4 v = *(const float4*)(src + i);
  ushort4 o;
  o.x = f32_to_bf16(v.x);
  o.y = f32_to_bf16(v.y);
  o.z = f32_to_bf16(v.z);
  o.w = f32_to_bf16(v.w);
  *(ushort4*)(dst + i) = o;
}

// ------------- GEMM core: C(128x128) = A_tile(128xK) * B_tile(128xK)^T ------
// global_load_lds staging (m97/m151 pattern). Single barrier per K-step.
__device__ __forceinline__ void gemm_core(const u16* __restrict__ A_tile,
                                          const u16* __restrict__ B_tile, int K,
                                          u16* As, u16* Bs, f32x4 acc[4][4]) {
  const int tid = threadIdx.x;
  const int w = tid >> 6, lane = tid & 63;
  const int wm = (w >> 1) << 6, wn = (w & 1) << 6;
  const int quad = lane >> 4, l15 = lane & 15;

  const u16* Ap = A_tile + (tid >> 2) * K + (tid & 3) * 8;
  const u16* Bp = B_tile + (tid >> 2) * K + (tid & 3) * 8;
  u16* Asw = As + w * 512;
  u16* Bsw = Bs + w * 512;

  // prologue: stage tile 0 into buffer 0
  gll16(Ap, Asw);
  gll16(Ap + 64 * K, Asw + 2048);
  gll16(Bp, Bsw);
  gll16(Bp + 64 * K, Bsw + 2048);

  int p = 0;
  for (int k0 = 0; k0 < K; k0 += BK) {
    const int kn = k0 + BK;
    __syncthreads();  // drains vmcnt: tile p staged; reads of p^1 done
    if (kn < K) {
      const int off = (p ^ 1) * TILE_ELEMS;
      gll16(Ap + kn, Asw + off);
      gll16(Ap + 64 * K + kn, Asw + off + 2048);
      gll16(Bp + kn, Bsw + off);
      gll16(Bp + 64 * K + kn, Bsw + off + 2048);
    }
    const u16* Asr = As + p * TILE_ELEMS;
    const u16* Bsr = Bs + p * TILE_ELEMS;
    bf16x8 af[4], bf[4];
#pragma unroll
    for (int i = 0; i < 4; i++)
      af[i] = *(const bf16x8*)(Asr + (wm + i * 16 + l15) * BK + quad * 8);
#pragma unroll
    for (int j = 0; j < 4; j++)
      bf[j] = *(const bf16x8*)(Bsr + (wn + j * 16 + l15) * BK + quad * 8);
#pragma unroll
    for (int i = 0; i < 4; i++)
#pragma unroll
      for (int j = 0; j < 4; j++)
        acc[i][j] =
            __builtin_amdgcn_mfma_f32_16x16x32_bf16(af[i], bf[j], acc[i][j], 0, 0, 0);
    p ^= 1;
  }
}

// ---------------- fused q-proj + latent-proj (q pre-scaled by QSCALE) -------
__global__ __launch_bounds__(256) void gemm_qlat(const u16* __restrict__ X,
                                                 const u16* __restrict__ QW,
                                                 const u16* __restrict__ KVDW,
                                                 const float* __restrict__ q_b,
                                                 const float* __restrict__ kvd_b,
                                                 u16* __restrict__ Qb,
                                                 u16* __restrict__ Lat) {
  __shared__ __align__(16) u16 As[2 * TILE_ELEMS];
  __shared__ __align__(16) u16 Bs[2 * TILE_ELEMS];
  int bn, bm;
  xcd_swz(bn, bm);
  const bool isq = bn < 16;
  const u16* B_tile = isq ? QW + (size_t)bn * 128 * 2048
                          : KVDW + (size_t)(bn - 16) * 128 * 2048;
  f32x4 acc[4][4];
  const f32x4 z = {0.f, 0.f, 0.f, 0.f};
#pragma unroll
  for (int i = 0; i < 4; i++)
#pragma unroll
    for (int j = 0; j < 4; j++) acc[i][j] = z;
  gemm_core(X + (size_t)bm * 128 * 2048, B_tile, 2048, As, Bs, acc);

  const float* bias = isq ? q_b : kvd_b;
  u16* C = isq ? Qb : Lat;
  const int N = isq ? 2048 : 512;
  const float scale = isq ? QSCALE : 1.0f;
  const int colbase = (isq ? bn : bn - 16) * 128;

  const int tid = threadIdx.x;
  const int w = tid >> 6, lane = tid & 63;
  const int wm = (w >> 1) << 6, wn = (w & 1) << 6;
  const int quad = lane >> 4, l15 = lane & 15;
  const int row0 = bm * 128 + wm + quad * 4;
  const int col0 = colbase + wn + l15;
#pragma unroll
  for (int i = 0; i < 4; i++)
#pragma unroll
    for (int j = 0; j < 4; j++) {
      int col = col0 + j * 16;
      float bv = bias[col];
#pragma unroll
      for (int r = 0; r < 4; r++) {
        int row = row0 + i * 16 + r;
        C[(size_t)row * N + col] = f32_to_bf16((acc[i][j][r] + bv) * scale);
      }
    }
}

// ---------------- GEMM with fp32 output (final projection) ----------------
__global__ __launch_bounds__(256) void gemm_f32out(const u16* __restrict__ A,
                                                   const u16* __restrict__ B,
                                                   const float* __restrict__ bias,
                                                   float* __restrict__ C, int K, int N) {
  __shared__ __align__(16) u16 As[2 * TILE_ELEMS];
  __shared__ __align__(16) u16 Bs[2 * TILE_ELEMS];
  int bn, bm;
  xcd_swz(bn, bm);
  f32x4 acc[4][4];
  const f32x4 z = {0.f, 0.f, 0.f, 0.f};
#pragma unroll
  for (int i = 0; i < 4; i++)
#pragma unroll
    for (int j = 0; j < 4; j++) acc[i][j] = z;
  gemm_core(A + (size_t)bm * 128 * K, B + (size_t)bn * 128 * K, K, As, Bs, acc);

  const int tid = threadIdx.x;
  const int w = tid >> 6, lane = tid & 63;
  const int wm = (w >> 1) << 6, wn = (w & 1) << 6;
  const int quad = lane >> 4, l15 = lane & 15;
  const int row0 = bm * 128 + wm + quad * 4;
  const int col0 = bn * 128 + wn + l15;
#pragma unroll
  for (int i = 0; i < 4; i++)
#pragma unroll
    for (int j = 0; j < 4; j++) {
      int col = col0 + j * 16;
      float bv = bias[col];
#pragma unroll
      for (int r = 0; r < 4; r++) {
        int row = row0 + i * 16 + r;
        C[(size_t)row * N + col] = acc[i][j][r] + bv;
      }
    }
}

// ------------- GEMM3: kv-up with scatter epilogue: K->(b,h,s,d), V->(b,h,d,s) -
__global__ __launch_bounds__(256) void gemm_kv(const u16* __restrict__ A,
                                               const u16* __restrict__ B,
                                               const float* __restrict__ bias,
                                               u16* __restrict__ Khat,
                                               u16* __restrict__ Vt, int K) {
  __shared__ __align__(16) u16 As[2 * TILE_ELEMS];
  __shared__ __align__(16) u16 Bs[2 * TILE_ELEMS];
  int bn, bm;
  xcd_swz(bn, bm);
  f32x4 acc[4][4];
  const f32x4 z = {0.f, 0.f, 0.f, 0.f};
#pragma unroll
  for (int i = 0; i < 4; i++)
#pragma unroll
    for (int j = 0; j < 4; j++) acc[i][j] = z;
  gemm_core(A + (size_t)bm * 128 * K, B + (size_t)bn * 128 * K, K, As, Bs, acc);

  const int tid = threadIdx.x;
  const int w = tid >> 6, lane = tid & 63;
  const int wm = (w >> 1) << 6, wn = (w & 1) << 6;
  const int quad = lane >> 4, l15 = lane & 15;
  const int row0 = bm * 128 + wm + quad * 4;
  const int col0 = bn * 128 + wn + l15;
#pragma unroll
  for (int i = 0; i < 4; i++)
#pragma unroll
    for (int j = 0; j < 4; j++) {
      int n = col0 + j * 16;
      float bv = bias[n];
#pragma unroll
      for (int r = 0; r < 4; r++) {
        int row = row0 + i * 16 + r;   // row = b*2048 + s
        int bb = row >> 11, s = row & 2047;
        u16 val = f32_to_bf16(acc[i][j][r] + bv);
        if (n < 2048) {
          int h = n >> 7, d = n & 127;
          Khat[((size_t)(bb * 16 + h) * 2048 + s) * 128 + d] = val;
        } else {
          int h = (n - 2048) >> 7, d = n & 127;
          Vt[((size_t)(bb * 16 + h) * 128 + d) * 2048 + s] = val;
        }
      }
    }
}

// ---------------- attention: S^T trick, 8-wave d-split blocks ---------------
// Round-13: 512-thread blocks, wave = (qgroup qg = w>>1, d-half dh = w&1).
// Each wave computes the full 32x32 QK^T for its q-group (duplicated with its
// d-partner) but PV/oacc for only 64 of 128 dims -> oacc 64->32 regs. With
// __launch_bounds__(512,4) the allocator targets <=128 VGPR -> 4 waves/SIMD
// (2 blocks x 8 waves per CU), doubling latency hiding vs the 2-wave/SIMD
// register wall diagnosed in round 5. LDS layout, staging tile shapes and
// barrier structure identical to the verified round-8 body; 512 threads cover
// exactly the 512 K-slots / 512 V-slots with one 16B chunk each.
__global__ __launch_bounds__(512, 4) void attn_kernel(const u16* __restrict__ Q,
                                                      const u16* __restrict__ Khat,
                                                      const u16* __restrict__ Vt,
                                                      u16* __restrict__ O) {
  __shared__ __align__(16) u16 Ks[2][32 * 136];   // keys x dims (stride 136)
  __shared__ __align__(16) u16 Vs[2][128 * 40];   // dims x keys-permuted (stride 40)

  const int tid = threadIdx.x;
  const int w = tid >> 6, lane = tid & 63;
  const int l31 = lane & 31, half = lane >> 5;
  const int qg = w >> 1, dh = w & 1;              // q-group 0..3, d-half 0..1
  const int idx = blockIdx.x;
  const int swz = (idx & 7) * 64 + (idx >> 3);    // 512 blocks: bijective
  const int qt = swz & 15;
  const int h = (swz >> 4) & 15;
  const int b = swz >> 8;
  const int bh = b * 16 + h;

  bf16x8 qf[8];
  {
    const u16* qrow = Q + (size_t)(b * 2048 + qt * 128 + qg * 32 + l31) * 2048 +
                      h * 128 + half * 8;
#pragma unroll
    for (int kc = 0; kc < 8; kc++) qf[kc] = *(const bf16x8*)(qrow + kc * 16);
  }

  f32x16 oacc[2];
#pragma unroll
  for (int nt = 0; nt < 2; nt++)
#pragma unroll
    for (int r = 0; r < 16; r++) oacc[nt][r] = 0.f;
  float ls0 = 0.f, ls1 = 0.f, ls2 = 0.f, ls3 = 0.f;

  const u16* Kg = Khat + (size_t)bh * 2048 * 128;
  const u16* Vg = Vt + (size_t)bh * 128 * 2048;

  // staging: 512 threads, one 16B chunk each.
  // K: 32 rows x 16 chunks; V: 128 dims x 4 chunks (permuted slots)
  const int kkr = tid >> 4, kc0 = tid & 15;
  const int vd = tid >> 2, vc0 = tid & 3;
  const int vlo = (vc0 >> 1) * 16 + (vc0 & 1) * 4;  // {0,4,16,20}
  const int vhi = vlo + 8;

  u16x8 kv, vv;
  kv = *(const u16x8*)(Kg + (size_t)kkr * 128 + kc0 * 8);
  vv = *(const u16x8*)(Vg + (size_t)vd * 2048 + vc0 * 8);
  {
    *(u16x8*)(Ks[0] + kkr * 136 + kc0 * 8) = kv;
    const unsigned long long* vp = (const unsigned long long*)&vv;
    *(unsigned long long*)(Vs[0] + vd * 40 + vlo) = vp[0];
    *(unsigned long long*)(Vs[0] + vd * 40 + vhi) = vp[1];
  }

  int p = 0;
  for (int key0 = 0; key0 < 2048; key0 += 32) {
    const int kn = (key0 + 32 < 2048) ? (key0 + 32) : 0;
    kv = *(const u16x8*)(Kg + (size_t)(kn + kkr) * 128 + kc0 * 8);
    vv = *(const u16x8*)(Vg + (size_t)vd * 2048 + kn + vc0 * 8);
    __syncthreads();

    // S^T = K Q^T : full 32 keys x 32 q-rows (duplicated across d-partners)
    f32x16 sacc;
#pragma unroll
    for (int r = 0; r < 16; r++) sacc[r] = 0.f;
    __builtin_amdgcn_s_setprio(1);
#pragma unroll
    for (int kc = 0; kc < 8; kc++) {
      bf16x8 kf = *(const bf16x8*)(Ks[p] + l31 * 136 + kc * 16 + half * 8);
      sacc = __builtin_amdgcn_mfma_f32_32x32x16_bf16(kf, qf[kc], sacc, 0, 0, 0);
    }
    __builtin_amdgcn_s_setprio(0);

    float e[16];
#pragma unroll
    for (int r = 0; r < 16; r++) e[r] = EXP2(sacc[r]);
    ls0 += e[0] + e[4] + e[8] + e[12];
    ls1 += e[1] + e[5] + e[9] + e[13];
    ls2 += e[2] + e[6] + e[10] + e[14];
    ls3 += e[3] + e[7] + e[11] + e[15];
    bf16x8 pa0, pa1;
#pragma unroll
    for (int i = 0; i < 8; i++) {
      pa0[i] = (__bf16)e[i];
      pa1[i] = (__bf16)e[8 + i];
    }

    // O += P V for this wave's 64 dims: nt = dh*2 + {0,1}
    __builtin_amdgcn_s_setprio(1);
#pragma unroll
    for (int nt2 = 0; nt2 < 2; nt2++) {
      const int nt = dh * 2 + nt2;
      bf16x8 vf0 = *(const bf16x8*)(Vs[p] + (nt * 32 + l31) * 40 + half * 8);
      bf16x8 vf1 = *(const bf16x8*)(Vs[p] + (nt * 32 + l31) * 40 + 16 + half * 8);
      oacc[nt2] = __builtin_amdgcn_mfma_f32_32x32x16_bf16(pa0, vf0, oacc[nt2], 0, 0, 0);
      oacc[nt2] = __builtin_amdgcn_mfma_f32_32x32x16_bf16(pa1, vf1, oacc[nt2], 0, 0, 0);
    }
    __builtin_amdgcn_s_setprio(0);

    const int pn = p ^ 1;
    {
      *(u16x8*)(Ks[pn] + kkr * 136 + kc0 * 8) = kv;
      const unsigned long long* vp = (const unsigned long long*)&vv;
      *(unsigned long long*)(Vs[pn] + vd * 40 + vlo) = vp[0];
      *(unsigned long long*)(Vs[pn] + vd * 40 + vhi) = vp[1];
    }
    p = pn;
  }

  // lanes l and l+32 hold complementary key-halves of q-row l31
  float lsum = (ls0 + ls1) + (ls2 + ls3);
  lsum += __shfl_xor(lsum, 32);
  float inv = 1.0f / lsum;
  float wr[16];
#pragma unroll
  for (int r = 0; r < 16; r++) {
    int ridx = (r & 3) + 8 * (r >> 2) + 4 * half;
    wr[r] = __shfl(inv, ridx);
  }

#pragma unroll
  for (int nt2 = 0; nt2 < 2; nt2++)
#pragma unroll
    for (int r = 0; r < 16; r++) {
      int ridx = (r & 3) + 8 * (r >> 2) + 4 * half;
      int row = b * 2048 + qt * 128 + qg * 32 + ridx;
      int col = h * 128 + (dh * 2 + nt2) * 32 + l31;
      O[(size_t)row * 2048 + col] = f32_to_bf16(oacc[nt2][r] * wr[r]);
    }
}

// ---------------- launch ----------------
extern "C" void kernel_launch(void* const* d_in, const int* in_sizes, int n_in,
                              void* d_out, int out_size, void* d_ws, size_t ws_size,
                              hipStream_t stream) {
  (void)in_sizes; (void)n_in; (void)out_size; (void)ws_size;
  const float* x     = (const float*)d_in[0];
  const float* q_w   = (const float*)d_in[1];
  const float* q_b   = (const float*)d_in[2];
  const float* kvd_w = (const float*)d_in[3];
  const float* kvd_b = (const float*)d_in[4];
  const float* kvu_w = (const float*)d_in[5];
  const float* kvu_b = (const float*)d_in[6];
  const float* out_w = (const float*)d_in[7];
  const float* out_b = (const float*)d_in[8];
  float* out = (float*)d_out;

  // Workspace (106 MB): X 16 | W1 8 | W2 2 | W3 4 | W4 8 | Qb 16 | Lat 4 |
  // Khat 16 | Vt 16 | AO 16
  char* p = (char*)d_ws;
  u16* X    = (u16*)(p + 0);
  u16* W1   = (u16*)(p + (size_t)16 * 1024 * 1024);
  u16* W2   = (u16*)(p + (size_t)24 * 1024 * 1024);
  u16* W3   = (u16*)(p + (size_t)26 * 1024 * 1024);
  u16* W4   = (u16*)(p + (size_t)30 * 1024 * 1024);
  u16* Qb   = (u16*)(p + (size_t)38 * 1024 * 1024);
  u16* Lat  = (u16*)(p + (size_t)54 * 1024 * 1024);
  u16* Khat = (u16*)(p + (size_t)58 * 1024 * 1024);
  u16* Vt   = (u16*)(p + (size_t)74 * 1024 * 1024);
  u16* AO   = (u16*)(p + (size_t)90 * 1024 * 1024);

  cvt_all<<<dim3(19456), dim3(256), 0, stream>>>(x, q_w, kvd_w, kvu_w, out_w,
                                                 X, W1, W2, W3, W4);
  gemm_qlat<<<dim3(20, 32), dim3(256), 0, stream>>>(X, W1, W2, q_b, kvd_b, Qb, Lat);
  gemm_kv<<<dim3(32, 32), dim3(256), 0, stream>>>(Lat, W3, kvu_b, Khat, Vt, 512);
  attn_kernel<<<dim3(512), dim3(512), 0, stream>>>(Qb, Khat, Vt, AO);
  gemm_f32out<<<dim3(16, 32), dim3(256), 0, stream>>>(AO, W4, out_b, out, 2048, 2048);
}

// Round 15
// 357.631 us; speedup vs baseline: 1.0760x; 1.0760x over previous
//
#include <hip/hip_runtime.h>

typedef unsigned short u16;
typedef __attribute__((ext_vector_type(8))) __bf16 bf16x8;
typedef __attribute__((ext_vector_type(8))) unsigned short u16x8;
typedef __attribute__((ext_vector_type(4))) float f32x4;
typedef __attribute__((ext_vector_type(16))) float f32x16;

#define BK 32
#define TILE_ELEMS (128 * BK)
// softmax scale folded into q-projection: 1/sqrt(128) * log2(e)
#define QSCALE 0.12753706518066536f

#if __has_builtin(__builtin_amdgcn_exp2f)
#define EXP2(x) __builtin_amdgcn_exp2f(x)
#else
#define EXP2(x) exp2f(x)
#endif

// Native HW convert: compiler fuses adjacent casts into v_cvt_pk_bf16_f32.
__device__ __forceinline__ u16 f32_to_bf16(float f) {
  __bf16 h = (__bf16)f;
  return __builtin_bit_cast(u16, h);
}

// async global->LDS, 16B per lane. LDS dest must be wave-uniform base;
// HW stores lane i at base + i*16.
__device__ __forceinline__ void gll16(const u16* g, u16* l) {
  __builtin_amdgcn_global_load_lds(
      (const __attribute__((address_space(1))) void*)g,
      (__attribute__((address_space(3))) void*)l, 16, 0, 0);
}

// T1 XCD-aware swizzle (m157/m192): give each XCD a contiguous wgid chunk so
// neighboring tiles (sharing A-panels / B-panels) hit the same per-XCD L2.
// Requires nwg % 8 == 0 (true for all three GEMM grids: 640 / 1024 / 512).
__device__ __forceinline__ void xcd_swz(int& bn, int& bm) {
  const int nx = gridDim.x;
  const int nwg = nx * gridDim.y;
  const int wg = blockIdx.y * nx + blockIdx.x;
  const int cpx = nwg >> 3;
  const int swz = (wg & 7) * cpx + (wg >> 3);
  bn = swz % nx;
  bm = swz / nx;
}

// ---------------- fused fp32 -> bf16 conversion (all 5 tensors) -------------
__global__ __launch_bounds__(256) void cvt_all(
    const float* __restrict__ x, const float* __restrict__ qw,
    const float* __restrict__ kvdw, const float* __restrict__ kvuw,
    const float* __restrict__ outw, u16* __restrict__ X, u16* __restrict__ W1,
    u16* __restrict__ W2, u16* __restrict__ W3, u16* __restrict__ W4) {
  int blk = blockIdx.x;
  const float* src;
  u16* dst;
  int base;
  if (blk < 8192)       { src = x;    dst = X;  base = blk; }
  else if (blk < 12288) { src = qw;   dst = W1; base = blk - 8192; }
  else if (blk < 13312) { src = kvdw; dst = W2; base = blk - 12288; }
  else if (blk < 15360) { src = kvuw; dst = W3; base = blk - 13312; }
  else                  { src = outw; dst = W4; base = blk - 15360; }
  int i = base * 1024 + threadIdx.x * 4;
  float4 v = *(const float4*)(src + i);
  ushort4 o;
  o.x = f32_to_bf16(v.x);
  o.y = f32_to_bf16(v.y);
  o.z = f32_to_bf16(v.z);
  o.w = f32_to_bf16(v.w);
  *(ushort4*)(dst + i) = o;
}

// ------------- GEMM core: C(128x128) = A_tile(128xK) * B_tile(128xK)^T ------
// global_load_lds staging (m97/m151 pattern). Single barrier per K-step.
__device__ __forceinline__ void gemm_core(const u16* __restrict__ A_tile,
                                          const u16* __restrict__ B_tile, int K,
                                          u16* As, u16* Bs, f32x4 acc[4][4]) {
  const int tid = threadIdx.x;
  const int w = tid >> 6, lane = tid & 63;
  const int wm = (w >> 1) << 6, wn = (w & 1) << 6;
  const int quad = lane >> 4, l15 = lane & 15;

  const u16* Ap = A_tile + (tid >> 2) * K + (tid & 3) * 8;
  const u16* Bp = B_tile + (tid >> 2) * K + (tid & 3) * 8;
  u16* Asw = As + w * 512;
  u16* Bsw = Bs + w * 512;

  // prologue: stage tile 0 into buffer 0
  gll16(Ap, Asw);
  gll16(Ap + 64 * K, Asw + 2048);
  gll16(Bp, Bsw);
  gll16(Bp + 64 * K, Bsw + 2048);

  int p = 0;
  for (int k0 = 0; k0 < K; k0 += BK) {
    const int kn = k0 + BK;
    __syncthreads();  // drains vmcnt: tile p staged; reads of p^1 done
    if (kn < K) {
      const int off = (p ^ 1) * TILE_ELEMS;
      gll16(Ap + kn, Asw + off);
      gll16(Ap + 64 * K + kn, Asw + off + 2048);
      gll16(Bp + kn, Bsw + off);
      gll16(Bp + 64 * K + kn, Bsw + off + 2048);
    }
    const u16* Asr = As + p * TILE_ELEMS;
    const u16* Bsr = Bs + p * TILE_ELEMS;
    bf16x8 af[4], bf[4];
#pragma unroll
    for (int i = 0; i < 4; i++)
      af[i] = *(const bf16x8*)(Asr + (wm + i * 16 + l15) * BK + quad * 8);
#pragma unroll
    for (int j = 0; j < 4; j++)
      bf[j] = *(const bf16x8*)(Bsr + (wn + j * 16 + l15) * BK + quad * 8);
#pragma unroll
    for (int i = 0; i < 4; i++)
#pragma unroll
      for (int j = 0; j < 4; j++)
        acc[i][j] =
            __builtin_amdgcn_mfma_f32_16x16x32_bf16(af[i], bf[j], acc[i][j], 0, 0, 0);
    p ^= 1;
  }
}

// ---------------- fused q-proj + latent-proj (q pre-scaled by QSCALE) -------
__global__ __launch_bounds__(256) void gemm_qlat(const u16* __restrict__ X,
                                                 const u16* __restrict__ QW,
                                                 const u16* __restrict__ KVDW,
                                                 const float* __restrict__ q_b,
                                                 const float* __restrict__ kvd_b,
                                                 u16* __restrict__ Qb,
                                                 u16* __restrict__ Lat) {
  __shared__ __align__(16) u16 As[2 * TILE_ELEMS];
  __shared__ __align__(16) u16 Bs[2 * TILE_ELEMS];
  int bn, bm;
  xcd_swz(bn, bm);
  const bool isq = bn < 16;
  const u16* B_tile = isq ? QW + (size_t)bn * 128 * 2048
                          : KVDW + (size_t)(bn - 16) * 128 * 2048;
  f32x4 acc[4][4];
  const f32x4 z = {0.f, 0.f, 0.f, 0.f};
#pragma unroll
  for (int i = 0; i < 4; i++)
#pragma unroll
    for (int j = 0; j < 4; j++) acc[i][j] = z;
  gemm_core(X + (size_t)bm * 128 * 2048, B_tile, 2048, As, Bs, acc);

  const float* bias = isq ? q_b : kvd_b;
  u16* C = isq ? Qb : Lat;
  const int N = isq ? 2048 : 512;
  const float scale = isq ? QSCALE : 1.0f;
  const int colbase = (isq ? bn : bn - 16) * 128;

  const int tid = threadIdx.x;
  const int w = tid >> 6, lane = tid & 63;
  const int wm = (w >> 1) << 6, wn = (w & 1) << 6;
  const int quad = lane >> 4, l15 = lane & 15;
  const int row0 = bm * 128 + wm + quad * 4;
  const int col0 = colbase + wn + l15;
#pragma unroll
  for (int i = 0; i < 4; i++)
#pragma unroll
    for (int j = 0; j < 4; j++) {
      int col = col0 + j * 16;
      float bv = bias[col];
#pragma unroll
      for (int r = 0; r < 4; r++) {
        int row = row0 + i * 16 + r;
        C[(size_t)row * N + col] = f32_to_bf16((acc[i][j][r] + bv) * scale);
      }
    }
}

// ---------------- GEMM with fp32 output (final projection) ----------------
__global__ __launch_bounds__(256) void gemm_f32out(const u16* __restrict__ A,
                                                   const u16* __restrict__ B,
                                                   const float* __restrict__ bias,
                                                   float* __restrict__ C, int K, int N) {
  __shared__ __align__(16) u16 As[2 * TILE_ELEMS];
  __shared__ __align__(16) u16 Bs[2 * TILE_ELEMS];
  int bn, bm;
  xcd_swz(bn, bm);
  f32x4 acc[4][4];
  const f32x4 z = {0.f, 0.f, 0.f, 0.f};
#pragma unroll
  for (int i = 0; i < 4; i++)
#pragma unroll
    for (int j = 0; j < 4; j++) acc[i][j] = z;
  gemm_core(A + (size_t)bm * 128 * K, B + (size_t)bn * 128 * K, K, As, Bs, acc);

  const int tid = threadIdx.x;
  const int w = tid >> 6, lane = tid & 63;
  const int wm = (w >> 1) << 6, wn = (w & 1) << 6;
  const int quad = lane >> 4, l15 = lane & 15;
  const int row0 = bm * 128 + wm + quad * 4;
  const int col0 = bn * 128 + wn + l15;
#pragma unroll
  for (int i = 0; i < 4; i++)
#pragma unroll
    for (int j = 0; j < 4; j++) {
      int col = col0 + j * 16;
      float bv = bias[col];
#pragma unroll
      for (int r = 0; r < 4; r++) {
        int row = row0 + i * 16 + r;
        C[(size_t)row * N + col] = acc[i][j][r] + bv;
      }
    }
}

// ------------- GEMM3: kv-up with scatter epilogue: K->(b,h,s,d), V->(b,h,d,s) -
// V is written with the attention PV slot-permutation PRE-BAKED: within each
// 16-key group, slot(k) swaps bits 2<->3 of k (verified against the old
// vlo/vhi={0,4,16,20} staging table in both directions). The permutation
// preserves 4-element contiguity (r-loop writes stay consecutive since row0
// is 4-aligned), so the scatter cost is unchanged; attention then stages V
// with plain linear 16B writes.
__global__ __launch_bounds__(256) void gemm_kv(const u16* __restrict__ A,
                                               const u16* __restrict__ B,
                                               const float* __restrict__ bias,
                                               u16* __restrict__ Khat,
                                               u16* __restrict__ Vt, int K) {
  __shared__ __align__(16) u16 As[2 * TILE_ELEMS];
  __shared__ __align__(16) u16 Bs[2 * TILE_ELEMS];
  int bn, bm;
  xcd_swz(bn, bm);
  f32x4 acc[4][4];
  const f32x4 z = {0.f, 0.f, 0.f, 0.f};
#pragma unroll
  for (int i = 0; i < 4; i++)
#pragma unroll
    for (int j = 0; j < 4; j++) acc[i][j] = z;
  gemm_core(A + (size_t)bm * 128 * K, B + (size_t)bn * 128 * K, K, As, Bs, acc);

  const int tid = threadIdx.x;
  const int w = tid >> 6, lane = tid & 63;
  const int wm = (w >> 1) << 6, wn = (w & 1) << 6;
  const int quad = lane >> 4, l15 = lane & 15;
  const int row0 = bm * 128 + wm + quad * 4;
  const int col0 = bn * 128 + wn + l15;
#pragma unroll
  for (int i = 0; i < 4; i++)
#pragma unroll
    for (int j = 0; j < 4; j++) {
      int n = col0 + j * 16;
      float bv = bias[n];
#pragma unroll
      for (int r = 0; r < 4; r++) {
        int row = row0 + i * 16 + r;   // row = b*2048 + s
        int bb = row >> 11, s = row & 2047;
        u16 val = f32_to_bf16(acc[i][j][r] + bv);
        if (n < 2048) {
          int h = n >> 7, d = n & 127;
          Khat[((size_t)(bb * 16 + h) * 2048 + s) * 128 + d] = val;
        } else {
          int h = (n - 2048) >> 7, d = n & 127;
          // slot permutation: swap bits 2<->3 within each 16-key group
          int sp = (s & ~15) | (s & 3) | ((s >> 1) & 4) | ((s << 1) & 8);
          Vt[((size_t)(bb * 16 + h) * 128 + d) * 2048 + sp] = val;
        }
      }
    }
}

// ---------------- attention: S^T trick — P stays in registers ----------------
// Round-15 = round-14 source resubmitted unchanged (GPUAcquisitionTimeout was
// pure infra; source never ran). Round-8 verified body with V pre-permuted in
// Vt (gemm_kv bakes the slot permutation), so V staging is a single linear
// 16B ds_write per chunk instead of two 8B permuted writes. LDS staging
// (K stride 136, V stride 40), XCD-chunked block swizzle, s_setprio around
// MFMA clusters, single QK accumulator chain.
__global__ __launch_bounds__(256) void attn_kernel(const u16* __restrict__ Q,
                                                   const u16* __restrict__ Khat,
                                                   const u16* __restrict__ Vt,
                                                   u16* __restrict__ O) {
  __shared__ __align__(16) u16 Ks[2][32 * 136];   // keys x dims (stride 136)
  __shared__ __align__(16) u16 Vs[2][128 * 40];   // dims x keys (pre-permuted)

  const int tid = threadIdx.x;
  const int w = tid >> 6, lane = tid & 63;
  const int l31 = lane & 31, half = lane >> 5;
  const int idx = blockIdx.x;
  const int swz = (idx & 7) * 64 + (idx >> 3);    // 512 blocks: bijective
  const int qt = swz & 15;
  const int h = (swz >> 4) & 15;
  const int b = swz >> 8;
  const int bh = b * 16 + h;

  bf16x8 qf[8];
  {
    const u16* qrow = Q + (size_t)(b * 2048 + qt * 128 + w * 32 + l31) * 2048 +
                      h * 128 + half * 8;
#pragma unroll
    for (int kc = 0; kc < 8; kc++) qf[kc] = *(const bf16x8*)(qrow + kc * 16);
  }

  f32x16 oacc[4];
#pragma unroll
  for (int nt = 0; nt < 4; nt++)
#pragma unroll
    for (int r = 0; r < 16; r++) oacc[nt][r] = 0.f;
  float ls0 = 0.f, ls1 = 0.f, ls2 = 0.f, ls3 = 0.f;

  const u16* Kg = Khat + (size_t)bh * 2048 * 128;
  const u16* Vg = Vt + (size_t)bh * 128 * 2048;

  const int kkr = tid >> 4, kc0 = tid & 15;
  const int vd = tid >> 2, vc0 = tid & 3;

  u16x8 kv[2], vv[2];
#pragma unroll
  for (int it = 0; it < 2; it++) {
    kv[it] = *(const u16x8*)(Kg + (size_t)(kkr + it * 16) * 128 + kc0 * 8);
    vv[it] = *(const u16x8*)(Vg + (size_t)(vd + it * 64) * 2048 + vc0 * 8);
  }
#pragma unroll
  for (int it = 0; it < 2; it++) {
    *(u16x8*)(Ks[0] + (kkr + it * 16) * 136 + kc0 * 8) = kv[it];
    *(u16x8*)(Vs[0] + (vd + it * 64) * 40 + vc0 * 8) = vv[it];
  }

  int p = 0;
  for (int key0 = 0; key0 < 2048; key0 += 32) {
    const int kn = (key0 + 32 < 2048) ? (key0 + 32) : 0;
#pragma unroll
    for (int it = 0; it < 2; it++) {
      kv[it] = *(const u16x8*)(Kg + (size_t)(kn + kkr + it * 16) * 128 + kc0 * 8);
      vv[it] = *(const u16x8*)(Vg + (size_t)(vd + it * 64) * 2048 + kn + vc0 * 8);
    }
    __syncthreads();

    f32x16 sacc;
#pragma unroll
    for (int r = 0; r < 16; r++) sacc[r] = 0.f;
    __builtin_amdgcn_s_setprio(1);
#pragma unroll
    for (int kc = 0; kc < 8; kc++) {
      bf16x8 kf = *(const bf16x8*)(Ks[p] + l31 * 136 + kc * 16 + half * 8);
      sacc = __builtin_amdgcn_mfma_f32_32x32x16_bf16(kf, qf[kc], sacc, 0, 0, 0);
    }
    __builtin_amdgcn_s_setprio(0);

    float e[16];
#pragma unroll
    for (int r = 0; r < 16; r++) e[r] = EXP2(sacc[r]);
    ls0 += e[0] + e[4] + e[8] + e[12];
    ls1 += e[1] + e[5] + e[9] + e[13];
    ls2 += e[2] + e[6] + e[10] + e[14];
    ls3 += e[3] + e[7] + e[11] + e[15];
    bf16x8 pa0, pa1;
#pragma unroll
    for (int i = 0; i < 8; i++) {
      pa0[i] = (__bf16)e[i];
      pa1[i] = (__bf16)e[8 + i];
    }

    __builtin_amdgcn_s_setprio(1);
#pragma unroll
    for (int nt = 0; nt < 4; nt++) {
      bf16x8 vf0 = *(const bf16x8*)(Vs[p] + (nt * 32 + l31) * 40 + half * 8);
      bf16x8 vf1 = *(const bf16x8*)(Vs[p] + (nt * 32 + l31) * 40 + 16 + half * 8);
      oacc[nt] = __builtin_amdgcn_mfma_f32_32x32x16_bf16(pa0, vf0, oacc[nt], 0, 0, 0);
      oacc[nt] = __builtin_amdgcn_mfma_f32_32x32x16_bf16(pa1, vf1, oacc[nt], 0, 0, 0);
    }
    __builtin_amdgcn_s_setprio(0);

    const int pn = p ^ 1;
#pragma unroll
    for (int it = 0; it < 2; it++) {
      *(u16x8*)(Ks[pn] + (kkr + it * 16) * 136 + kc0 * 8) = kv[it];
      *(u16x8*)(Vs[pn] + (vd + it * 64) * 40 + vc0 * 8) = vv[it];
    }
    p = pn;
  }

  float lsum = (ls0 + ls1) + (ls2 + ls3);
  lsum += __shfl_xor(lsum, 32);
  float inv = 1.0f / lsum;
  float wr[16];
#pragma unroll
  for (int r = 0; r < 16; r++) {
    int ridx = (r & 3) + 8 * (r >> 2) + 4 * half;
    wr[r] = __shfl(inv, ridx);
  }

#pragma unroll
  for (int nt = 0; nt < 4; nt++)
#pragma unroll
    for (int r = 0; r < 16; r++) {
      int ridx = (r & 3) + 8 * (r >> 2) + 4 * half;
      int row = b * 2048 + qt * 128 + w * 32 + ridx;
      int col = h * 128 + nt * 32 + l31;
      O[(size_t)row * 2048 + col] = f32_to_bf16(oacc[nt][r] * wr[r]);
    }
}

// ---------------- launch ----------------
extern "C" void kernel_launch(void* const* d_in, const int* in_sizes, int n_in,
                              void* d_out, int out_size, void* d_ws, size_t ws_size,
                              hipStream_t stream) {
  (void)in_sizes; (void)n_in; (void)out_size; (void)ws_size;
  const float* x     = (const float*)d_in[0];
  const float* q_w   = (const float*)d_in[1];
  const float* q_b   = (const float*)d_in[2];
  const float* kvd_w = (const float*)d_in[3];
  const float* kvd_b = (const float*)d_in[4];
  const float* kvu_w = (const float*)d_in[5];
  const float* kvu_b = (const float*)d_in[6];
  const float* out_w = (const float*)d_in[7];
  const float* out_b = (const float*)d_in[8];
  float* out = (float*)d_out;

  // Workspace (106 MB): X 16 | W1 8 | W2 2 | W3 4 | W4 8 | Qb 16 | Lat 4 |
  // Khat 16 | Vt 16 | AO 16
  char* p = (char*)d_ws;
  u16* X    = (u16*)(p + 0);
  u16* W1   = (u16*)(p + (size_t)16 * 1024 * 1024);
  u16* W2   = (u16*)(p + (size_t)24 * 1024 * 1024);
  u16* W3   = (u16*)(p + (size_t)26 * 1024 * 1024);
  u16* W4   = (u16*)(p + (size_t)30 * 1024 * 1024);
  u16* Qb   = (u16*)(p + (size_t)38 * 1024 * 1024);
  u16* Lat  = (u16*)(p + (size_t)54 * 1024 * 1024);
  u16* Khat = (u16*)(p + (size_t)58 * 1024 * 1024);
  u16* Vt   = (u16*)(p + (size_t)74 * 1024 * 1024);
  u16* AO   = (u16*)(p + (size_t)90 * 1024 * 1024);

  cvt_all<<<dim3(19456), dim3(256), 0, stream>>>(x, q_w, kvd_w, kvu_w, out_w,
                                                 X, W1, W2, W3, W4);
  gemm_qlat<<<dim3(20, 32), dim3(256), 0, stream>>>(X, W1, W2, q_b, kvd_b, Qb, Lat);
  gemm_kv<<<dim3(32, 32), dim3(256), 0, stream>>>(Lat, W3, kvu_b, Khat, Vt, 512);
  attn_kernel<<<dim3(512), dim3(256), 0, stream>>>(Qb, Khat, Vt, AO);
  gemm_f32out<<<dim3(16, 32), dim3(256), 0, stream>>>(AO, W4, out_b, out, 2048, 2048);
}